// Round 3
// baseline (3894.819 us; speedup 1.0000x reference)
//
#include <hip/hip_runtime.h>

#define N_USERS 100000
#define N_ITEMS 50000
#define N_NODES (N_USERS + N_ITEMS)   // 150000
#define DIM 64
#define NNZ_TOTAL 10000000
#define TOTAL (N_NODES * DIM)         // 9,600,000 floats
#define TOTAL4 (TOTAL / 4)            // 2,400,000 float4
#define USZ4 (N_USERS * DIM / 4)      // 1,600,000 float4

#define BROWS 256                     // rows per bucket
#define NBUCKETS ((N_NODES + BROWS - 1) / BROWS)   // 586
#define COLMASK 0x3FFFF               // 18 bits for col (< 262144)

// ===========================================================================
// init: A = concat(user, item); acc(d_out) = same
// ===========================================================================
__global__ __launch_bounds__(256) void k_init(const float4* __restrict__ user,
                                              const float4* __restrict__ item,
                                              float4* __restrict__ A,
                                              float4* __restrict__ acc) {
    const int stride = gridDim.x * blockDim.x;
    for (int i = blockIdx.x * blockDim.x + threadIdx.x; i < TOTAL4; i += stride) {
        float4 v = (i < USZ4) ? user[i] : item[i - USZ4];
        A[i] = v;
        acc[i] = v;
    }
}

// ===========================================================================
// Bucketed CSR build
// ===========================================================================
// 1) per-block LDS histogram of bucket sizes
__global__ __launch_bounds__(256) void k_bhist(const int* __restrict__ row,
                                               int* __restrict__ bcnt) {
    __shared__ int h[NBUCKETS];
    for (int i = threadIdx.x; i < NBUCKETS; i += 256) h[i] = 0;
    __syncthreads();
    const int stride = gridDim.x * blockDim.x;
    for (int e = blockIdx.x * blockDim.x + threadIdx.x; e < NNZ_TOTAL; e += stride) {
        atomicAdd(&h[row[e] >> 8], 1);
    }
    __syncthreads();
    for (int i = threadIdx.x; i < NBUCKETS; i += 256) {
        if (h[i]) atomicAdd(&bcnt[i], h[i]);
    }
}

// 2) exclusive scan of 586 bucket counts (single block), also init cursors
__global__ __launch_bounds__(1024) void k_bscan(const int* __restrict__ bcnt,
                                                int* __restrict__ bbase,
                                                int* __restrict__ bcur) {
    __shared__ int lds[1024];
    const int tid = threadIdx.x;
    const int x = (tid < NBUCKETS) ? bcnt[tid] : 0;
    lds[tid] = x;
    __syncthreads();
    for (int off = 1; off < 1024; off <<= 1) {
        const int y = (tid >= off) ? lds[tid - off] : 0;
        __syncthreads();
        lds[tid] += y;
        __syncthreads();
    }
    const int excl = lds[tid] - x;
    if (tid < NBUCKETS) {
        bbase[tid] = excl;
        bcur[tid] = excl;
    }
    if (tid == NBUCKETS) bbase[NBUCKETS] = excl;   // == total == NNZ
}

// 3) append edges into bucket regions (dense writes)
__global__ __launch_bounds__(256) void k_bappend(const int* __restrict__ row,
                                                 const int* __restrict__ col,
                                                 const float* __restrict__ val,
                                                 int* __restrict__ bcur,
                                                 uint2* __restrict__ tmp) {
    const int stride = gridDim.x * blockDim.x;
    for (int e = blockIdx.x * blockDim.x + threadIdx.x; e < NNZ_TOTAL; e += stride) {
        const int r = row[e];
        const int b = r >> 8;
        const unsigned meta = ((unsigned)(r & 255) << 18) | (unsigned)col[e];
        const int p = atomicAdd(&bcur[b], 1);
        tmp[p] = make_uint2(meta, __float_as_uint(val[e]));
    }
}

// 4) per-bucket counting sort: bucket region is ~137 KB -> L2-resident scatter
__global__ __launch_bounds__(256) void k_bsort(const uint2* __restrict__ tmp,
                                               uint2* __restrict__ csr,
                                               const int* __restrict__ bbase,
                                               int* __restrict__ row_offs) {
    __shared__ int cnt[BROWS];
    __shared__ int sc[BROWS];
    __shared__ int curl[BROWS];
    const int tid = threadIdx.x;
    const int b = blockIdx.x;
    const int s = bbase[b];
    const int e = bbase[b + 1];

    cnt[tid] = 0;
    __syncthreads();
    for (int j = s + tid; j < e; j += 256) {
        atomicAdd(&cnt[tmp[j].x >> 18], 1);
    }
    __syncthreads();
    // exclusive scan of 256 counts
    const int x = cnt[tid];
    sc[tid] = x;
    __syncthreads();
    for (int off = 1; off < 256; off <<= 1) {
        const int y = (tid >= off) ? sc[tid - off] : 0;
        __syncthreads();
        sc[tid] += y;
        __syncthreads();
    }
    const int excl = sc[tid] - x;
    const int gr = b * BROWS + tid;
    if (gr < N_NODES) row_offs[gr] = s + excl;
    curl[tid] = s + excl;
    __syncthreads();
    for (int j = s + tid; j < e; j += 256) {
        const uint2 u = tmp[j];
        const int p = atomicAdd(&curl[u.x >> 18], 1);
        csr[p] = u;
    }
    if (b == 0 && tid == 0) row_offs[N_NODES] = NNZ_TOTAL;
}

// ===========================================================================
// CSR SpMM: one wave per row; lane = sub*16 + d4. Packed (meta,val) edges,
// unroll-2 (two 256B gathers in flight). acc update fused.
// ===========================================================================
template <bool FINAL>
__global__ __launch_bounds__(256) void k_spmm_csr(const float4* __restrict__ A4,
                                                  float4* __restrict__ B4,
                                                  float4* __restrict__ ACC4,
                                                  const int* __restrict__ offs,
                                                  const uint2* __restrict__ csr) {
    const int lane = threadIdx.x & 63;
    const int sub  = lane >> 4;
    const int d4   = lane & 15;
    const int r = blockIdx.x * 4 + (threadIdx.x >> 6);
    if (r >= N_NODES) return;
    const int s = offs[r];
    const int e = offs[r + 1];
    float4 acc = make_float4(0.f, 0.f, 0.f, 0.f);
    int j = s + sub;
    for (; j + 4 < e; j += 8) {
        const uint2 e0 = csr[j];
        const uint2 e1 = csr[j + 4];
        const float4 g0 = A4[(size_t)(e0.x & COLMASK) * 16 + d4];
        const float4 g1 = A4[(size_t)(e1.x & COLMASK) * 16 + d4];
        const float v0 = __uint_as_float(e0.y);
        const float v1 = __uint_as_float(e1.y);
        acc.x += v0 * g0.x + v1 * g1.x;
        acc.y += v0 * g0.y + v1 * g1.y;
        acc.z += v0 * g0.z + v1 * g1.z;
        acc.w += v0 * g0.w + v1 * g1.w;
    }
    if (j < e) {
        const uint2 e0 = csr[j];
        const float4 g0 = A4[(size_t)(e0.x & COLMASK) * 16 + d4];
        const float v0 = __uint_as_float(e0.y);
        acc.x += v0 * g0.x;
        acc.y += v0 * g0.y;
        acc.z += v0 * g0.z;
        acc.w += v0 * g0.w;
    }
    #pragma unroll
    for (int m = 16; m <= 32; m <<= 1) {
        acc.x += __shfl_xor(acc.x, m, 64);
        acc.y += __shfl_xor(acc.y, m, 64);
        acc.z += __shfl_xor(acc.z, m, 64);
        acc.w += __shfl_xor(acc.w, m, 64);
    }
    if (sub == 0) {
        const size_t idx = (size_t)r * 16 + d4;
        float4 a = ACC4[idx];
        if (FINAL) {
            a.x = (a.x + acc.x) * 0.25f;
            a.y = (a.y + acc.y) * 0.25f;
            a.z = (a.z + acc.z) * 0.25f;
            a.w = (a.w + acc.w) * 0.25f;
            ACC4[idx] = a;
        } else {
            B4[idx] = acc;
            a.x += acc.x;
            a.y += acc.y;
            a.z += acc.z;
            a.w += acc.w;
            ACC4[idx] = a;
        }
    }
}

// ===========================================================================
// Fallback paths (round-2 exact-scatter CSR, round-1 atomics)
// ===========================================================================
__global__ __launch_bounds__(256) void k_hist(const int* __restrict__ row,
                                              int* __restrict__ counts) {
    const int stride = gridDim.x * blockDim.x;
    for (int e = blockIdx.x * blockDim.x + threadIdx.x; e < NNZ_TOTAL; e += stride)
        atomicAdd(&counts[row[e]], 1);
}

__global__ __launch_bounds__(1024) void k_scan(const int* __restrict__ counts,
                                               int* __restrict__ offs) {
    __shared__ int lds[1024];
    __shared__ int carry;
    const int tid = threadIdx.x;
    if (tid == 0) carry = 0;
    __syncthreads();
    for (int base = 0; base < N_NODES; base += 1024) {
        const int i = base + tid;
        const int x = (i < N_NODES) ? counts[i] : 0;
        lds[tid] = x;
        __syncthreads();
        int v = x;
        for (int off = 1; off < 1024; off <<= 1) {
            const int y = (tid >= off) ? lds[tid - off] : 0;
            __syncthreads();
            v += y;
            lds[tid] = v;
            __syncthreads();
        }
        if (i < N_NODES) offs[i] = carry + (v - x);
        __syncthreads();
        if (tid == 0) carry += lds[1023];
        __syncthreads();
    }
    if (tid == 0) offs[N_NODES] = carry;
}

__global__ __launch_bounds__(256) void k_copy_offs(const int* __restrict__ offs,
                                                   int* __restrict__ cur) {
    const int i = blockIdx.x * blockDim.x + threadIdx.x;
    if (i < N_NODES) cur[i] = offs[i];
}

__global__ __launch_bounds__(256) void k_scatter_pk(const int* __restrict__ row,
                                                    const int* __restrict__ col,
                                                    const float* __restrict__ val,
                                                    int* __restrict__ cur,
                                                    uint2* __restrict__ csr) {
    const int stride = gridDim.x * blockDim.x;
    for (int e = blockIdx.x * blockDim.x + threadIdx.x; e < NNZ_TOTAL; e += stride) {
        const int p = atomicAdd(&cur[row[e]], 1);
        csr[p] = make_uint2((unsigned)col[e], __float_as_uint(val[e]));
    }
}

__global__ __launch_bounds__(256) void k_spmm_atomic(const float* __restrict__ A,
                                                     float* __restrict__ B,
                                                     const float* __restrict__ val,
                                                     const int* __restrict__ row,
                                                     const int* __restrict__ col) {
    const int lane = threadIdx.x & 63;
    int wave = blockIdx.x * (blockDim.x >> 6) + (threadIdx.x >> 6);
    const int nw = gridDim.x * (blockDim.x >> 6);
    for (int e = wave; e < NNZ_TOTAL; e += nw) {
        const float x = A[col[e] * DIM + lane];
        unsafeAtomicAdd(&B[row[e] * DIM + lane], val[e] * x);
    }
}

__global__ __launch_bounds__(256) void k_accadd(float4* __restrict__ acc,
                                                const float4* __restrict__ B) {
    const int stride = gridDim.x * blockDim.x;
    for (int i = blockIdx.x * blockDim.x + threadIdx.x; i < TOTAL4; i += stride) {
        float4 a = acc[i];
        const float4 b = B[i];
        a.x += b.x; a.y += b.y; a.z += b.z; a.w += b.w;
        acc[i] = a;
    }
}

__global__ __launch_bounds__(256) void k_final(float4* __restrict__ acc,
                                               const float4* __restrict__ B) {
    const int stride = gridDim.x * blockDim.x;
    for (int i = blockIdx.x * blockDim.x + threadIdx.x; i < TOTAL4; i += stride) {
        float4 a = acc[i];
        const float4 b = B[i];
        a.x = (a.x + b.x) * 0.25f;
        a.y = (a.y + b.y) * 0.25f;
        a.z = (a.z + b.z) * 0.25f;
        a.w = (a.w + b.w) * 0.25f;
        acc[i] = a;
    }
}

extern "C" void kernel_launch(void* const* d_in, const int* in_sizes, int n_in,
                              void* d_out, int out_size, void* d_ws, size_t ws_size,
                              hipStream_t stream) {
    const float* user = (const float*)d_in[0];
    const float* item = (const float*)d_in[1];
    const float* val  = (const float*)d_in[2];
    const int*   row  = (const int*)d_in[3];
    const int*   col  = (const int*)d_in[4];

    float* acc = (float*)d_out;
    const int eltBlocks = 2048;

    // ---- preferred layout: [csr 80MB][tmp 80MB, later A+B][misc] ----
    const size_t CSR_BYTES = (size_t)NNZ_TOTAL * 8;            // 80,000,000
    uint2* csr  = (uint2*)d_ws;
    char*  reg1 = (char*)d_ws + CSR_BYTES;
    uint2* tmp  = (uint2*)reg1;
    float* A    = (float*)reg1;                                 // overlays tmp after build
    float* B    = A + TOTAL;
    int* bcnt     = (int*)(reg1 + CSR_BYTES);
    int* bbase    = bcnt + NBUCKETS;                            // NBUCKETS+1
    int* bcur     = bbase + NBUCKETS + 1;
    int* row_offs = bcur + NBUCKETS;                            // N_NODES+1

    const size_t needed_new =
        2 * CSR_BYTES + (size_t)(NBUCKETS * 3 + 1 + N_NODES + 1) * 4;

    if (ws_size >= needed_new) {
        // ---- bucketed CSR build ----
        hipMemsetAsync(bcnt, 0, (size_t)NBUCKETS * sizeof(int), stream);
        k_bhist<<<1024, 256, 0, stream>>>(row, bcnt);
        k_bscan<<<1, 1024, 0, stream>>>(bcnt, bbase, bcur);
        k_bappend<<<2048, 256, 0, stream>>>(row, col, val, bcur, tmp);
        k_bsort<<<NBUCKETS, 256, 0, stream>>>(tmp, csr, bbase, row_offs);

        // ---- embeddings (A/B overlay tmp; tmp is dead now) ----
        k_init<<<eltBlocks, 256, 0, stream>>>((const float4*)user, (const float4*)item,
                                              (float4*)A, (float4*)acc);

        const int rowBlocks = N_NODES / 4;
        k_spmm_csr<false><<<rowBlocks, 256, 0, stream>>>(
            (const float4*)A, (float4*)B, (float4*)acc, row_offs, csr);
        k_spmm_csr<false><<<rowBlocks, 256, 0, stream>>>(
            (const float4*)B, (float4*)A, (float4*)acc, row_offs, csr);
        k_spmm_csr<true><<<rowBlocks, 256, 0, stream>>>(
            (const float4*)A, (float4*)B, (float4*)acc, row_offs, csr);
        return;
    }

    // ---- fallback: round-2 style exact scatter (packed) ----
    float* A2    = (float*)d_ws;                 // TOTAL
    float* B2    = A2 + TOTAL;                   // TOTAL
    uint2* csr2  = (uint2*)(B2 + TOTAL);         // NNZ u64
    int* counts  = (int*)(csr2 + NNZ_TOTAL);     // N_NODES
    int* offs2   = counts + N_NODES;             // N_NODES+1
    int* cur2    = offs2 + N_NODES + 1;          // N_NODES
    const size_t needed_old =
        ((size_t)2 * TOTAL + (size_t)3 * N_NODES + 1) * 4 + (size_t)NNZ_TOTAL * 8;

    k_init<<<eltBlocks, 256, 0, stream>>>((const float4*)user, (const float4*)item,
                                          (float4*)A2, (float4*)acc);

    if (ws_size >= needed_old) {
        hipMemsetAsync(counts, 0, (size_t)N_NODES * sizeof(int), stream);
        k_hist<<<2048, 256, 0, stream>>>(row, counts);
        k_scan<<<1, 1024, 0, stream>>>(counts, offs2);
        k_copy_offs<<<(N_NODES + 255) / 256, 256, 0, stream>>>(offs2, cur2);
        k_scatter_pk<<<2048, 256, 0, stream>>>(row, col, val, cur2, csr2);

        const int rowBlocks = N_NODES / 4;
        k_spmm_csr<false><<<rowBlocks, 256, 0, stream>>>(
            (const float4*)A2, (float4*)B2, (float4*)acc, offs2, csr2);
        k_spmm_csr<false><<<rowBlocks, 256, 0, stream>>>(
            (const float4*)B2, (float4*)A2, (float4*)acc, offs2, csr2);
        k_spmm_csr<true><<<rowBlocks, 256, 0, stream>>>(
            (const float4*)A2, (float4*)B2, (float4*)acc, offs2, csr2);
    } else {
        // ---- last resort: atomic path ----
        float* Af = A2;
        float* Bf = B2;
        for (int layer = 0; layer < 3; ++layer) {
            hipMemsetAsync(Bf, 0, (size_t)TOTAL * sizeof(float), stream);
            k_spmm_atomic<<<2048, 256, 0, stream>>>(Af, Bf, val, row, col);
            if (layer < 2) {
                k_accadd<<<eltBlocks, 256, 0, stream>>>((float4*)acc, (const float4*)Bf);
                float* t = Af; Af = Bf; Bf = t;
            } else {
                k_final<<<eltBlocks, 256, 0, stream>>>((float4*)acc, (const float4*)Bf);
            }
        }
    }
}

// Round 4
// 2266.826 us; speedup vs baseline: 1.7182x; 1.7182x over previous
//
#include <hip/hip_runtime.h>

#define N_USERS 100000
#define N_ITEMS 50000
#define N_NODES (N_USERS + N_ITEMS)   // 150000
#define DIM 64
#define NNZ_TOTAL 10000000
#define TOTAL (N_NODES * DIM)         // 9,600,000 floats
#define TOTAL4 (TOTAL / 4)            // 2,400,000 float4
#define USZ4 (N_USERS * DIM / 4)      // 1,600,000 float4

#define BROWS 16                      // rows per bucket
#define KSUB 4                        // cursor shards per bucket
#define NBUCKETS (N_NODES / BROWS)    // 9375 (exact)
#define NKEYS (NBUCKETS * KSUB)       // 37500
#define COLMASK 0x3FFFF               // 18 bits for col (< 262144)

__device__ __forceinline__ int edge_key(int r, int e) {
    return ((r >> 4) << 2) | (e & 3);
}

// ===========================================================================
// init: A = concat(user, item); acc(d_out) = same
// ===========================================================================
__global__ __launch_bounds__(256) void k_init(const float4* __restrict__ user,
                                              const float4* __restrict__ item,
                                              float4* __restrict__ A,
                                              float4* __restrict__ acc) {
    const int stride = gridDim.x * blockDim.x;
    for (int i = blockIdx.x * blockDim.x + threadIdx.x; i < TOTAL4; i += stride) {
        float4 v = (i < USZ4) ? user[i] : item[i - USZ4];
        A[i] = v;
        acc[i] = v;
    }
}

// ===========================================================================
// Bucketed CSR build (37500 sharded cursors -> ~267 atomics per cursor)
// ===========================================================================
// 1) global histogram over keys
__global__ __launch_bounds__(256) void k_bhist(const int* __restrict__ row,
                                               int* __restrict__ bcnt) {
    const int stride = gridDim.x * blockDim.x;
    for (int e = blockIdx.x * blockDim.x + threadIdx.x; e < NNZ_TOTAL; e += stride) {
        atomicAdd(&bcnt[edge_key(row[e], e)], 1);
    }
}

// 2) single-block exclusive scan over NKEYS (chunked: each thread owns CH keys)
__global__ __launch_bounds__(1024) void k_bscan(const int* __restrict__ bcnt,
                                                int* __restrict__ bbase,
                                                int* __restrict__ bcur) {
    __shared__ int lds[1024];
    const int CH = (NKEYS + 1023) / 1024;   // 37
    const int t = threadIdx.x;
    const int lo = t * CH;
    const int hi = (lo + CH < NKEYS) ? lo + CH : NKEYS;
    int s = 0;
    for (int i = lo; i < hi; ++i) s += bcnt[i];
    lds[t] = s;
    __syncthreads();
    for (int off = 1; off < 1024; off <<= 1) {
        const int y = (t >= off) ? lds[t - off] : 0;
        __syncthreads();
        lds[t] += y;
        __syncthreads();
    }
    int base = lds[t] - s;                  // exclusive prefix of this chunk
    for (int i = lo; i < hi; ++i) {
        const int c = bcnt[i];
        bbase[i] = base;
        bcur[i] = base;
        base += c;
    }
    if (t == 1023) bbase[NKEYS] = lds[1023];
}

// 3) append edges into sub-bucket regions (dense writes, shallow chains)
__global__ __launch_bounds__(256) void k_bappend(const int* __restrict__ row,
                                                 const int* __restrict__ col,
                                                 const float* __restrict__ val,
                                                 int* __restrict__ bcur,
                                                 uint2* __restrict__ tmp) {
    const int stride = gridDim.x * blockDim.x;
    for (int e = blockIdx.x * blockDim.x + threadIdx.x; e < NNZ_TOTAL; e += stride) {
        const int r = row[e];
        const unsigned meta = ((unsigned)(r & (BROWS - 1)) << 18) | (unsigned)col[e];
        const int p = atomicAdd(&bcur[edge_key(r, e)], 1);
        tmp[p] = make_uint2(meta, __float_as_uint(val[e]));
    }
}

// 4) per-bucket counting sort: one block per 16-row bucket (~1067 edges, ~8.5KB)
__global__ __launch_bounds__(256) void k_bsort(const uint2* __restrict__ tmp,
                                               uint2* __restrict__ csr,
                                               const int* __restrict__ bbase,
                                               int* __restrict__ row_offs) {
    __shared__ int cnt[BROWS];
    __shared__ int roff[BROWS];
    __shared__ int curl[BROWS];
    const int tid = threadIdx.x;
    const int b = blockIdx.x;
    const int s = bbase[b * KSUB];
    const int e = bbase[b * KSUB + KSUB];   // contiguous: sub-slots are adjacent

    if (tid < BROWS) cnt[tid] = 0;
    __syncthreads();
    for (int j = s + tid; j < e; j += 256) {
        atomicAdd(&cnt[tmp[j].x >> 18], 1);
    }
    __syncthreads();
    if (tid == 0) {
        int a = 0;
        #pragma unroll
        for (int k = 0; k < BROWS; ++k) { roff[k] = a; a += cnt[k]; }
    }
    __syncthreads();
    if (tid < BROWS) {
        row_offs[b * BROWS + tid] = s + roff[tid];
        curl[tid] = s + roff[tid];
    }
    __syncthreads();
    for (int j = s + tid; j < e; j += 256) {
        const uint2 u = tmp[j];
        const int p = atomicAdd(&curl[u.x >> 18], 1);
        csr[p] = u;
    }
    if (b == 0 && tid == 0) row_offs[N_NODES] = NNZ_TOTAL;
}

// ===========================================================================
// CSR SpMM: one wave per row; lane = sub*16 + d4. Packed (meta,val) edges,
// unroll-2 (two 256B gathers in flight). acc update fused.
// ===========================================================================
template <bool FINAL>
__global__ __launch_bounds__(256) void k_spmm_csr(const float4* __restrict__ A4,
                                                  float4* __restrict__ B4,
                                                  float4* __restrict__ ACC4,
                                                  const int* __restrict__ offs,
                                                  const uint2* __restrict__ csr) {
    const int lane = threadIdx.x & 63;
    const int sub  = lane >> 4;
    const int d4   = lane & 15;
    const int r = blockIdx.x * 4 + (threadIdx.x >> 6);
    if (r >= N_NODES) return;
    const int s = offs[r];
    const int e = offs[r + 1];
    float4 acc = make_float4(0.f, 0.f, 0.f, 0.f);
    int j = s + sub;
    for (; j + 4 < e; j += 8) {
        const uint2 e0 = csr[j];
        const uint2 e1 = csr[j + 4];
        const float4 g0 = A4[(size_t)(e0.x & COLMASK) * 16 + d4];
        const float4 g1 = A4[(size_t)(e1.x & COLMASK) * 16 + d4];
        const float v0 = __uint_as_float(e0.y);
        const float v1 = __uint_as_float(e1.y);
        acc.x += v0 * g0.x + v1 * g1.x;
        acc.y += v0 * g0.y + v1 * g1.y;
        acc.z += v0 * g0.z + v1 * g1.z;
        acc.w += v0 * g0.w + v1 * g1.w;
    }
    if (j < e) {
        const uint2 e0 = csr[j];
        const float4 g0 = A4[(size_t)(e0.x & COLMASK) * 16 + d4];
        const float v0 = __uint_as_float(e0.y);
        acc.x += v0 * g0.x;
        acc.y += v0 * g0.y;
        acc.z += v0 * g0.z;
        acc.w += v0 * g0.w;
    }
    #pragma unroll
    for (int m = 16; m <= 32; m <<= 1) {
        acc.x += __shfl_xor(acc.x, m, 64);
        acc.y += __shfl_xor(acc.y, m, 64);
        acc.z += __shfl_xor(acc.z, m, 64);
        acc.w += __shfl_xor(acc.w, m, 64);
    }
    if (sub == 0) {
        const size_t idx = (size_t)r * 16 + d4;
        float4 a = ACC4[idx];
        if (FINAL) {
            a.x = (a.x + acc.x) * 0.25f;
            a.y = (a.y + acc.y) * 0.25f;
            a.z = (a.z + acc.z) * 0.25f;
            a.w = (a.w + acc.w) * 0.25f;
            ACC4[idx] = a;
        } else {
            B4[idx] = acc;
            a.x += acc.x;
            a.y += acc.y;
            a.z += acc.z;
            a.w += acc.w;
            ACC4[idx] = a;
        }
    }
}

// ===========================================================================
// Fallback paths (round-2 exact-scatter CSR, round-1 atomics)
// ===========================================================================
__global__ __launch_bounds__(256) void k_hist(const int* __restrict__ row,
                                              int* __restrict__ counts) {
    const int stride = gridDim.x * blockDim.x;
    for (int e = blockIdx.x * blockDim.x + threadIdx.x; e < NNZ_TOTAL; e += stride)
        atomicAdd(&counts[row[e]], 1);
}

__global__ __launch_bounds__(1024) void k_scan(const int* __restrict__ counts,
                                               int* __restrict__ offs) {
    __shared__ int lds[1024];
    __shared__ int carry;
    const int tid = threadIdx.x;
    if (tid == 0) carry = 0;
    __syncthreads();
    for (int base = 0; base < N_NODES; base += 1024) {
        const int i = base + tid;
        const int x = (i < N_NODES) ? counts[i] : 0;
        lds[tid] = x;
        __syncthreads();
        int v = x;
        for (int off = 1; off < 1024; off <<= 1) {
            const int y = (tid >= off) ? lds[tid - off] : 0;
            __syncthreads();
            v += y;
            lds[tid] = v;
            __syncthreads();
        }
        if (i < N_NODES) offs[i] = carry + (v - x);
        __syncthreads();
        if (tid == 0) carry += lds[1023];
        __syncthreads();
    }
    if (tid == 0) offs[N_NODES] = carry;
}

__global__ __launch_bounds__(256) void k_copy_offs(const int* __restrict__ offs,
                                                   int* __restrict__ cur) {
    const int i = blockIdx.x * blockDim.x + threadIdx.x;
    if (i < N_NODES) cur[i] = offs[i];
}

__global__ __launch_bounds__(256) void k_scatter_pk(const int* __restrict__ row,
                                                    const int* __restrict__ col,
                                                    const float* __restrict__ val,
                                                    int* __restrict__ cur,
                                                    uint2* __restrict__ csr) {
    const int stride = gridDim.x * blockDim.x;
    for (int e = blockIdx.x * blockDim.x + threadIdx.x; e < NNZ_TOTAL; e += stride) {
        const int p = atomicAdd(&cur[row[e]], 1);
        csr[p] = make_uint2((unsigned)col[e], __float_as_uint(val[e]));
    }
}

__global__ __launch_bounds__(256) void k_spmm_atomic(const float* __restrict__ A,
                                                     float* __restrict__ B,
                                                     const float* __restrict__ val,
                                                     const int* __restrict__ row,
                                                     const int* __restrict__ col) {
    const int lane = threadIdx.x & 63;
    int wave = blockIdx.x * (blockDim.x >> 6) + (threadIdx.x >> 6);
    const int nw = gridDim.x * (blockDim.x >> 6);
    for (int e = wave; e < NNZ_TOTAL; e += nw) {
        const float x = A[col[e] * DIM + lane];
        unsafeAtomicAdd(&B[row[e] * DIM + lane], val[e] * x);
    }
}

__global__ __launch_bounds__(256) void k_accadd(float4* __restrict__ acc,
                                                const float4* __restrict__ B) {
    const int stride = gridDim.x * blockDim.x;
    for (int i = blockIdx.x * blockDim.x + threadIdx.x; i < TOTAL4; i += stride) {
        float4 a = acc[i];
        const float4 b = B[i];
        a.x += b.x; a.y += b.y; a.z += b.z; a.w += b.w;
        acc[i] = a;
    }
}

__global__ __launch_bounds__(256) void k_final(float4* __restrict__ acc,
                                               const float4* __restrict__ B) {
    const int stride = gridDim.x * blockDim.x;
    for (int i = blockIdx.x * blockDim.x + threadIdx.x; i < TOTAL4; i += stride) {
        float4 a = acc[i];
        const float4 b = B[i];
        a.x = (a.x + b.x) * 0.25f;
        a.y = (a.y + b.y) * 0.25f;
        a.z = (a.z + b.z) * 0.25f;
        a.w = (a.w + b.w) * 0.25f;
        acc[i] = a;
    }
}

extern "C" void kernel_launch(void* const* d_in, const int* in_sizes, int n_in,
                              void* d_out, int out_size, void* d_ws, size_t ws_size,
                              hipStream_t stream) {
    const float* user = (const float*)d_in[0];
    const float* item = (const float*)d_in[1];
    const float* val  = (const float*)d_in[2];
    const int*   row  = (const int*)d_in[3];
    const int*   col  = (const int*)d_in[4];

    float* acc = (float*)d_out;
    const int eltBlocks = 2048;

    // ---- preferred layout: [csr 80MB][tmp 80MB, later A+B][misc] ----
    const size_t CSR_BYTES = (size_t)NNZ_TOTAL * 8;            // 80,000,000
    uint2* csr  = (uint2*)d_ws;
    char*  reg1 = (char*)d_ws + CSR_BYTES;
    uint2* tmp  = (uint2*)reg1;
    float* A    = (float*)reg1;                                 // overlays tmp after build
    float* B    = A + TOTAL;
    int* bcnt     = (int*)(reg1 + CSR_BYTES);                   // NKEYS
    int* bbase    = bcnt + NKEYS;                               // NKEYS+1
    int* bcur     = bbase + NKEYS + 1;                          // NKEYS
    int* row_offs = bcur + NKEYS;                               // N_NODES+1

    const size_t needed_new =
        2 * CSR_BYTES + (size_t)(3 * NKEYS + 1 + N_NODES + 1) * 4;

    if (ws_size >= needed_new) {
        // ---- bucketed CSR build (sharded cursors) ----
        hipMemsetAsync(bcnt, 0, (size_t)NKEYS * sizeof(int), stream);
        k_bhist<<<2048, 256, 0, stream>>>(row, bcnt);
        k_bscan<<<1, 1024, 0, stream>>>(bcnt, bbase, bcur);
        k_bappend<<<2048, 256, 0, stream>>>(row, col, val, bcur, tmp);
        k_bsort<<<NBUCKETS, 256, 0, stream>>>(tmp, csr, bbase, row_offs);

        // ---- embeddings (A/B overlay tmp; tmp is dead now) ----
        k_init<<<eltBlocks, 256, 0, stream>>>((const float4*)user, (const float4*)item,
                                              (float4*)A, (float4*)acc);

        const int rowBlocks = N_NODES / 4;
        k_spmm_csr<false><<<rowBlocks, 256, 0, stream>>>(
            (const float4*)A, (float4*)B, (float4*)acc, row_offs, csr);
        k_spmm_csr<false><<<rowBlocks, 256, 0, stream>>>(
            (const float4*)B, (float4*)A, (float4*)acc, row_offs, csr);
        k_spmm_csr<true><<<rowBlocks, 256, 0, stream>>>(
            (const float4*)A, (float4*)B, (float4*)acc, row_offs, csr);
        return;
    }

    // ---- fallback: round-2 style exact scatter (packed) ----
    float* A2    = (float*)d_ws;                 // TOTAL
    float* B2    = A2 + TOTAL;                   // TOTAL
    uint2* csr2  = (uint2*)(B2 + TOTAL);         // NNZ u64
    int* counts  = (int*)(csr2 + NNZ_TOTAL);     // N_NODES
    int* offs2   = counts + N_NODES;             // N_NODES+1
    int* cur2    = offs2 + N_NODES + 1;          // N_NODES
    const size_t needed_old =
        ((size_t)2 * TOTAL + (size_t)3 * N_NODES + 1) * 4 + (size_t)NNZ_TOTAL * 8;

    k_init<<<eltBlocks, 256, 0, stream>>>((const float4*)user, (const float4*)item,
                                          (float4*)A2, (float4*)acc);

    if (ws_size >= needed_old) {
        hipMemsetAsync(counts, 0, (size_t)N_NODES * sizeof(int), stream);
        k_hist<<<2048, 256, 0, stream>>>(row, counts);
        k_scan<<<1, 1024, 0, stream>>>(counts, offs2);
        k_copy_offs<<<(N_NODES + 255) / 256, 256, 0, stream>>>(offs2, cur2);
        k_scatter_pk<<<2048, 256, 0, stream>>>(row, col, val, cur2, csr2);

        const int rowBlocks = N_NODES / 4;
        k_spmm_csr<false><<<rowBlocks, 256, 0, stream>>>(
            (const float4*)A2, (float4*)B2, (float4*)acc, offs2, csr2);
        k_spmm_csr<false><<<rowBlocks, 256, 0, stream>>>(
            (const float4*)B2, (float4*)A2, (float4*)acc, offs2, csr2);
        k_spmm_csr<true><<<rowBlocks, 256, 0, stream>>>(
            (const float4*)A2, (float4*)B2, (float4*)acc, offs2, csr2);
    } else {
        float* Af = A2;
        float* Bf = B2;
        for (int layer = 0; layer < 3; ++layer) {
            hipMemsetAsync(Bf, 0, (size_t)TOTAL * sizeof(float), stream);
            k_spmm_atomic<<<2048, 256, 0, stream>>>(Af, Bf, val, row, col);
            if (layer < 2) {
                k_accadd<<<eltBlocks, 256, 0, stream>>>((float4*)acc, (const float4*)Bf);
                float* t = Af; Af = Bf; Bf = t;
            } else {
                k_final<<<eltBlocks, 256, 0, stream>>>((float4*)acc, (const float4*)Bf);
            }
        }
    }
}

// Round 5
// 1474.416 us; speedup vs baseline: 2.6416x; 1.5374x over previous
//
#include <hip/hip_runtime.h>

#define N_USERS 100000
#define N_ITEMS 50000
#define N_NODES (N_USERS + N_ITEMS)   // 150000
#define DIM 64
#define NNZ_TOTAL 10000000
#define TOTAL (N_NODES * DIM)         // 9,600,000 floats
#define TOTAL4 (TOTAL / 4)            // 2,400,000 float4
#define USZ4 (N_USERS * DIM / 4)      // 1,600,000 float4

#define BROWS 256                     // rows per bucket
#define NB ((N_NODES + BROWS - 1) / BROWS)   // 586
#define GRD 1024                      // radix blocks
#define CHUNK ((NNZ_TOTAL + GRD - 1) / GRD)  // 9766
#define NBG (NB * GRD)                // 600064 (divisible by 1024: 586/thread)
#define COLMASK 0x3FFFF               // 18 bits for col

__device__ __forceinline__ float bf2f(unsigned short u) {
    return __uint_as_float(((unsigned)u) << 16);
}
__device__ __forceinline__ unsigned short f2bf(float f) {
    unsigned b = __float_as_uint(f);
    b += 0x7FFFu + ((b >> 16) & 1u);   // RNE
    return (unsigned short)(b >> 16);
}

// ===========================================================================
// init: T0 = bf16(concat(user,item)); acc(d_out) = f32 concat
// ===========================================================================
__global__ __launch_bounds__(256) void k_init(const float4* __restrict__ user,
                                              const float4* __restrict__ item,
                                              ushort4* __restrict__ T0,
                                              float4* __restrict__ acc) {
    const int stride = gridDim.x * blockDim.x;
    for (int i = blockIdx.x * blockDim.x + threadIdx.x; i < TOTAL4; i += stride) {
        float4 v = (i < USZ4) ? user[i] : item[i - USZ4];
        acc[i] = v;
        ushort4 t;
        t.x = f2bf(v.x); t.y = f2bf(v.y); t.z = f2bf(v.z); t.w = f2bf(v.w);
        T0[i] = t;
    }
}

// ===========================================================================
// Radix-style bucket build: per-block hist -> scan -> exact-offset scatter
// ===========================================================================
__global__ __launch_bounds__(256) void k_lhist(const int* __restrict__ row,
                                               int* __restrict__ cnt) {
    __shared__ int h[NB];
    for (int i = threadIdx.x; i < NB; i += 256) h[i] = 0;
    __syncthreads();
    const int g = blockIdx.x;
    const int lo = g * CHUNK;
    const int hi = (lo + CHUNK < NNZ_TOTAL) ? lo + CHUNK : NNZ_TOTAL;
    for (int e = lo + threadIdx.x; e < hi; e += 256)
        atomicAdd(&h[row[e] >> 8], 1);
    __syncthreads();
    for (int b = threadIdx.x; b < NB; b += 256)
        cnt[b * GRD + g] = h[b];
}

// in-place exclusive scan over cnt[NBG] (b-major), also emits bucket bases
__global__ __launch_bounds__(1024) void k_mscan(int* __restrict__ cnt,
                                                int* __restrict__ bbase) {
    __shared__ int lds[1024];
    const int t = threadIdx.x;
    const int CH = NBG / 1024;        // 586
    const int lo = t * CH;
    int s = 0;
    for (int i = 0; i < CH; ++i) s += cnt[lo + i];
    lds[t] = s;
    __syncthreads();
    for (int off = 1; off < 1024; off <<= 1) {
        const int y = (t >= off) ? lds[t - off] : 0;
        __syncthreads();
        lds[t] += y;
        __syncthreads();
    }
    int base = lds[t] - s;            // exclusive prefix of this thread's chunk
    for (int i = 0; i < CH; ++i) {
        const int idx = lo + i;
        const int c = cnt[idx];
        if ((idx & (GRD - 1)) == 0) bbase[idx / GRD] = base;
        cnt[idx] = base;
        base += c;
    }
    if (t == 1023) bbase[NB] = lds[1023];   // == NNZ
}

__global__ __launch_bounds__(256) void k_lscatter(const int* __restrict__ row,
                                                  const int* __restrict__ col,
                                                  const float* __restrict__ val,
                                                  const int* __restrict__ cnt,
                                                  uint2* __restrict__ tmp) {
    __shared__ int cur[NB];
    const int g = blockIdx.x;
    for (int b = threadIdx.x; b < NB; b += 256) cur[b] = cnt[b * GRD + g];
    __syncthreads();
    const int lo = g * CHUNK;
    const int hi = (lo + CHUNK < NNZ_TOTAL) ? lo + CHUNK : NNZ_TOTAL;
    for (int e = lo + threadIdx.x; e < hi; e += 256) {
        const int r = row[e];
        const int b = r >> 8;
        const unsigned meta = ((unsigned)(r & (BROWS - 1)) << 18) | (unsigned)col[e];
        const int p = atomicAdd(&cur[b], 1);
        tmp[p] = make_uint2(meta, __float_as_uint(val[e]));
    }
}

// per-bucket counting sort: bucket region ~137 KB -> L2-resident scatter
__global__ __launch_bounds__(256) void k_bsort(const uint2* __restrict__ tmp,
                                               uint2* __restrict__ csr,
                                               const int* __restrict__ bbase,
                                               int* __restrict__ row_offs) {
    __shared__ int cnt[BROWS];
    __shared__ int roff[BROWS];
    __shared__ int curl[BROWS];
    const int tid = threadIdx.x;
    const int b = blockIdx.x;
    const int s = bbase[b];
    const int e = bbase[b + 1];

    cnt[tid] = 0;
    __syncthreads();
    for (int j = s + tid; j < e; j += 256)
        atomicAdd(&cnt[tmp[j].x >> 18], 1);
    __syncthreads();
    if (tid == 0) {
        int a = 0;
        #pragma unroll
        for (int k = 0; k < BROWS; ++k) { roff[k] = a; a += cnt[k]; }
    }
    __syncthreads();
    {
        const int gr = b * BROWS + tid;
        if (gr < N_NODES) row_offs[gr] = s + roff[tid];
        curl[tid] = s + roff[tid];
    }
    __syncthreads();
    for (int j = s + tid; j < e; j += 256) {
        const uint2 u = tmp[j];
        const int p = atomicAdd(&curl[u.x >> 18], 1);
        csr[p] = u;
    }
    if (b == 0 && tid == 0) row_offs[N_NODES] = NNZ_TOTAL;
}

// ===========================================================================
// CSR SpMM, bf16 gather table: one wave per row; lane = sub*16 + d4.
// Accumulate f32; write next-layer bf16 table + f32 acc. Unroll-4 for MLP.
// ===========================================================================
template <bool FINAL>
__global__ __launch_bounds__(256) void k_spmm_bf16(const ushort4* __restrict__ T4,
                                                   ushort4* __restrict__ U4,
                                                   float4* __restrict__ ACC4,
                                                   const int* __restrict__ offs,
                                                   const uint2* __restrict__ csr) {
    const int lane = threadIdx.x & 63;
    const int sub  = lane >> 4;
    const int d4   = lane & 15;
    const int r = blockIdx.x * 4 + (threadIdx.x >> 6);
    const int s = offs[r];
    const int e = offs[r + 1];
    float4 acc = make_float4(0.f, 0.f, 0.f, 0.f);
    int j = s + sub;
    for (; j + 12 < e; j += 16) {
        const uint2 e0 = csr[j];
        const uint2 e1 = csr[j + 4];
        const uint2 e2 = csr[j + 8];
        const uint2 e3 = csr[j + 12];
        const ushort4 g0 = T4[(size_t)(e0.x & COLMASK) * 16 + d4];
        const ushort4 g1 = T4[(size_t)(e1.x & COLMASK) * 16 + d4];
        const ushort4 g2 = T4[(size_t)(e2.x & COLMASK) * 16 + d4];
        const ushort4 g3 = T4[(size_t)(e3.x & COLMASK) * 16 + d4];
        const float v0 = __uint_as_float(e0.y);
        const float v1 = __uint_as_float(e1.y);
        const float v2 = __uint_as_float(e2.y);
        const float v3 = __uint_as_float(e3.y);
        acc.x += v0 * bf2f(g0.x) + v1 * bf2f(g1.x) + v2 * bf2f(g2.x) + v3 * bf2f(g3.x);
        acc.y += v0 * bf2f(g0.y) + v1 * bf2f(g1.y) + v2 * bf2f(g2.y) + v3 * bf2f(g3.y);
        acc.z += v0 * bf2f(g0.z) + v1 * bf2f(g1.z) + v2 * bf2f(g2.z) + v3 * bf2f(g3.z);
        acc.w += v0 * bf2f(g0.w) + v1 * bf2f(g1.w) + v2 * bf2f(g2.w) + v3 * bf2f(g3.w);
    }
    for (; j + 4 < e; j += 8) {
        const uint2 e0 = csr[j];
        const uint2 e1 = csr[j + 4];
        const ushort4 g0 = T4[(size_t)(e0.x & COLMASK) * 16 + d4];
        const ushort4 g1 = T4[(size_t)(e1.x & COLMASK) * 16 + d4];
        const float v0 = __uint_as_float(e0.y);
        const float v1 = __uint_as_float(e1.y);
        acc.x += v0 * bf2f(g0.x) + v1 * bf2f(g1.x);
        acc.y += v0 * bf2f(g0.y) + v1 * bf2f(g1.y);
        acc.z += v0 * bf2f(g0.z) + v1 * bf2f(g1.z);
        acc.w += v0 * bf2f(g0.w) + v1 * bf2f(g1.w);
    }
    if (j < e) {
        const uint2 e0 = csr[j];
        const ushort4 g0 = T4[(size_t)(e0.x & COLMASK) * 16 + d4];
        const float v0 = __uint_as_float(e0.y);
        acc.x += v0 * bf2f(g0.x);
        acc.y += v0 * bf2f(g0.y);
        acc.z += v0 * bf2f(g0.z);
        acc.w += v0 * bf2f(g0.w);
    }
    #pragma unroll
    for (int m = 16; m <= 32; m <<= 1) {
        acc.x += __shfl_xor(acc.x, m, 64);
        acc.y += __shfl_xor(acc.y, m, 64);
        acc.z += __shfl_xor(acc.z, m, 64);
        acc.w += __shfl_xor(acc.w, m, 64);
    }
    if (sub == 0) {
        const size_t idx = (size_t)r * 16 + d4;
        float4 a = ACC4[idx];
        if (FINAL) {
            a.x = (a.x + acc.x) * 0.25f;
            a.y = (a.y + acc.y) * 0.25f;
            a.z = (a.z + acc.z) * 0.25f;
            a.w = (a.w + acc.w) * 0.25f;
            ACC4[idx] = a;
        } else {
            ushort4 t;
            t.x = f2bf(acc.x); t.y = f2bf(acc.y); t.z = f2bf(acc.z); t.w = f2bf(acc.w);
            U4[idx] = t;
            a.x += acc.x;
            a.y += acc.y;
            a.z += acc.z;
            a.w += acc.w;
            ACC4[idx] = a;
        }
    }
}

// ===========================================================================
// Last-resort fallback (round-1 atomic path; needs only 76.8 MB ws)
// ===========================================================================
__global__ __launch_bounds__(256) void k_init_f32(const float4* __restrict__ user,
                                                  const float4* __restrict__ item,
                                                  float4* __restrict__ A,
                                                  float4* __restrict__ acc) {
    const int stride = gridDim.x * blockDim.x;
    for (int i = blockIdx.x * blockDim.x + threadIdx.x; i < TOTAL4; i += stride) {
        float4 v = (i < USZ4) ? user[i] : item[i - USZ4];
        A[i] = v;
        acc[i] = v;
    }
}

__global__ __launch_bounds__(256) void k_spmm_atomic(const float* __restrict__ A,
                                                     float* __restrict__ B,
                                                     const float* __restrict__ val,
                                                     const int* __restrict__ row,
                                                     const int* __restrict__ col) {
    const int lane = threadIdx.x & 63;
    int wave = blockIdx.x * (blockDim.x >> 6) + (threadIdx.x >> 6);
    const int nw = gridDim.x * (blockDim.x >> 6);
    for (int e = wave; e < NNZ_TOTAL; e += nw) {
        const float x = A[col[e] * DIM + lane];
        unsafeAtomicAdd(&B[row[e] * DIM + lane], val[e] * x);
    }
}

__global__ __launch_bounds__(256) void k_accadd(float4* __restrict__ acc,
                                                const float4* __restrict__ B) {
    const int stride = gridDim.x * blockDim.x;
    for (int i = blockIdx.x * blockDim.x + threadIdx.x; i < TOTAL4; i += stride) {
        float4 a = acc[i];
        const float4 b = B[i];
        a.x += b.x; a.y += b.y; a.z += b.z; a.w += b.w;
        acc[i] = a;
    }
}

__global__ __launch_bounds__(256) void k_final(float4* __restrict__ acc,
                                               const float4* __restrict__ B) {
    const int stride = gridDim.x * blockDim.x;
    for (int i = blockIdx.x * blockDim.x + threadIdx.x; i < TOTAL4; i += stride) {
        float4 a = acc[i];
        const float4 b = B[i];
        a.x = (a.x + b.x) * 0.25f;
        a.y = (a.y + b.y) * 0.25f;
        a.z = (a.z + b.z) * 0.25f;
        a.w = (a.w + b.w) * 0.25f;
        acc[i] = a;
    }
}

extern "C" void kernel_launch(void* const* d_in, const int* in_sizes, int n_in,
                              void* d_out, int out_size, void* d_ws, size_t ws_size,
                              hipStream_t stream) {
    const float* user = (const float*)d_in[0];
    const float* item = (const float*)d_in[1];
    const float* val  = (const float*)d_in[2];
    const int*   row  = (const int*)d_in[3];
    const int*   col  = (const int*)d_in[4];

    float* acc = (float*)d_out;
    const int eltBlocks = 2048;

    // ws layout: [csr 80MB (overlay: cnt matrix during build)]
    //            [tmp 80MB (overlay: T0,T1 bf16 tables after bsort)]
    //            [misc: row_offs, bbase]
    const size_t CSR_BYTES = (size_t)NNZ_TOTAL * 8;            // 80,000,000
    uint2* csr  = (uint2*)d_ws;
    int*   cnt  = (int*)d_ws;                                   // NBG ints, dead before bsort writes csr
    char*  reg1 = (char*)d_ws + CSR_BYTES;
    uint2* tmp  = (uint2*)reg1;
    ushort4* T0 = (ushort4*)reg1;                               // TOTAL4 ushort4 = 19.2MB
    ushort4* T1 = T0 + TOTAL4;                                  // 19.2MB
    int* row_offs = (int*)(reg1 + CSR_BYTES);                   // N_NODES+1
    int* bbase    = row_offs + N_NODES + 1;                     // NB+1

    const size_t needed =
        2 * CSR_BYTES + (size_t)(N_NODES + 1 + NB + 1) * 4;

    if (ws_size >= needed) {
        // ---- build bucketed CSR (no global atomics) ----
        k_lhist<<<GRD, 256, 0, stream>>>(row, cnt);
        k_mscan<<<1, 1024, 0, stream>>>(cnt, bbase);
        k_lscatter<<<GRD, 256, 0, stream>>>(row, col, val, cnt, tmp);
        k_bsort<<<NB, 256, 0, stream>>>(tmp, csr, bbase, row_offs);

        // ---- embeddings (T0/T1 overlay tmp; tmp dead after bsort) ----
        k_init<<<eltBlocks, 256, 0, stream>>>((const float4*)user, (const float4*)item,
                                              T0, (float4*)acc);

        const int rowBlocks = N_NODES / 4;   // 37500
        k_spmm_bf16<false><<<rowBlocks, 256, 0, stream>>>(
            T0, T1, (float4*)acc, row_offs, csr);
        k_spmm_bf16<false><<<rowBlocks, 256, 0, stream>>>(
            T1, T0, (float4*)acc, row_offs, csr);
        k_spmm_bf16<true><<<rowBlocks, 256, 0, stream>>>(
            T0, T1, (float4*)acc, row_offs, csr);
        return;
    }

    // ---- last resort: atomic path ----
    float* A2 = (float*)d_ws;
    float* B2 = A2 + TOTAL;
    k_init_f32<<<eltBlocks, 256, 0, stream>>>((const float4*)user, (const float4*)item,
                                              (float4*)A2, (float4*)acc);
    float* Af = A2;
    float* Bf = B2;
    for (int layer = 0; layer < 3; ++layer) {
        hipMemsetAsync(Bf, 0, (size_t)TOTAL * sizeof(float), stream);
        k_spmm_atomic<<<2048, 256, 0, stream>>>(Af, Bf, val, row, col);
        if (layer < 2) {
            k_accadd<<<eltBlocks, 256, 0, stream>>>((float4*)acc, (const float4*)Bf);
            float* t = Af; Af = Bf; Bf = t;
        } else {
            k_final<<<eltBlocks, 256, 0, stream>>>((float4*)acc, (const float4*)Bf);
        }
    }
}

// Round 6
// 907.746 us; speedup vs baseline: 4.2906x; 1.6243x over previous
//
#include <hip/hip_runtime.h>

#define N_USERS 100000
#define N_ITEMS 50000
#define N_NODES (N_USERS + N_ITEMS)   // 150000
#define DIM 64
#define NNZ_TOTAL 10000000
#define TOTAL (N_NODES * DIM)         // 9,600,000 floats
#define TOTAL4 (TOTAL / 4)            // 2,400,000 float4
#define USZ4 (N_USERS * DIM / 4)      // 1,600,000 float4

#define BROWS 256                     // rows per bucket
#define NB ((N_NODES + BROWS - 1) / BROWS)   // 586
#define GRD 1024                      // radix blocks
#define CHUNK ((NNZ_TOTAL + GRD - 1) / GRD)  // 9766
#define NBG (NB * GRD)                // 600064
#define COLMASK 0x3FFFF               // 18 bits for col

__device__ __forceinline__ float bf2f(unsigned short u) {
    return __uint_as_float(((unsigned)u) << 16);
}
__device__ __forceinline__ unsigned short f2bf(float f) {
    unsigned b = __float_as_uint(f);
    b += 0x7FFFu + ((b >> 16) & 1u);   // RNE
    return (unsigned short)(b >> 16);
}

// ===========================================================================
// init: T0 = bf16(concat(user,item)); acc(d_out) = f32 concat
// ===========================================================================
__global__ __launch_bounds__(256) void k_init(const float4* __restrict__ user,
                                              const float4* __restrict__ item,
                                              ushort4* __restrict__ T0,
                                              float4* __restrict__ acc) {
    const int stride = gridDim.x * blockDim.x;
    for (int i = blockIdx.x * blockDim.x + threadIdx.x; i < TOTAL4; i += stride) {
        float4 v = (i < USZ4) ? user[i] : item[i - USZ4];
        acc[i] = v;
        ushort4 t;
        t.x = f2bf(v.x); t.y = f2bf(v.y); t.z = f2bf(v.z); t.w = f2bf(v.w);
        T0[i] = t;
    }
}

// ===========================================================================
// Radix-style bucket build: per-block hist -> 3-phase scan -> exact scatter
// cnt matrix layout: cnt[b * GRD + g]  (b-major)
// ===========================================================================
__global__ __launch_bounds__(256) void k_lhist(const int* __restrict__ row,
                                               int* __restrict__ cnt) {
    __shared__ int h[NB];
    for (int i = threadIdx.x; i < NB; i += 256) h[i] = 0;
    __syncthreads();
    const int g = blockIdx.x;
    const int lo = g * CHUNK;
    const int hi = (lo + CHUNK < NNZ_TOTAL) ? lo + CHUNK : NNZ_TOTAL;
    for (int e = lo + threadIdx.x; e < hi; e += 256)
        atomicAdd(&h[row[e] >> 8], 1);
    __syncthreads();
    for (int b = threadIdx.x; b < NB; b += 256)
        cnt[b * GRD + g] = h[b];
}

// scan phase 1: per-bucket row sums (586 blocks, coalesced)
__global__ __launch_bounds__(256) void k_rowsum(const int* __restrict__ cnt,
                                                int* __restrict__ rowsum) {
    __shared__ int lds[256];
    const int b = blockIdx.x;
    const int t = threadIdx.x;
    int s = 0;
    #pragma unroll
    for (int k = 0; k < GRD / 256; ++k) s += cnt[b * GRD + k * 256 + t];
    lds[t] = s;
    __syncthreads();
    #pragma unroll
    for (int off = 128; off > 0; off >>= 1) {
        if (t < off) lds[t] += lds[t + off];
        __syncthreads();
    }
    if (t == 0) rowsum[b] = lds[0];
}

// scan phase 2: exclusive scan of 586 row sums (single tiny block)
__global__ __launch_bounds__(1024) void k_sscan(const int* __restrict__ rowsum,
                                                int* __restrict__ bbase) {
    __shared__ int lds[1024];
    const int t = threadIdx.x;
    const int x = (t < NB) ? rowsum[t] : 0;
    lds[t] = x;
    __syncthreads();
    for (int off = 1; off < 1024; off <<= 1) {
        const int y = (t >= off) ? lds[t - off] : 0;
        __syncthreads();
        lds[t] += y;
        __syncthreads();
    }
    if (t < NB) bbase[t] = lds[t] - x;
    if (t == 1023) bbase[NB] = lds[1023];   // == NNZ
}

// scan phase 3: per-row exclusive scan + bucket base, in place (586 blocks)
__global__ __launch_bounds__(1024) void k_rowscan(int* __restrict__ cnt,
                                                  const int* __restrict__ bbase) {
    __shared__ int lds[1024];
    const int b = blockIdx.x;
    const int t = threadIdx.x;
    const int idx = b * GRD + t;
    const int x = cnt[idx];
    lds[t] = x;
    __syncthreads();
    for (int off = 1; off < 1024; off <<= 1) {
        const int y = (t >= off) ? lds[t - off] : 0;
        __syncthreads();
        lds[t] += y;
        __syncthreads();
    }
    cnt[idx] = bbase[b] + lds[t] - x;       // exclusive + base
}

__global__ __launch_bounds__(256) void k_lscatter(const int* __restrict__ row,
                                                  const int* __restrict__ col,
                                                  const float* __restrict__ val,
                                                  const int* __restrict__ cnt,
                                                  uint2* __restrict__ tmp) {
    __shared__ int cur[NB];
    const int g = blockIdx.x;
    for (int b = threadIdx.x; b < NB; b += 256) cur[b] = cnt[b * GRD + g];
    __syncthreads();
    const int lo = g * CHUNK;
    const int hi = (lo + CHUNK < NNZ_TOTAL) ? lo + CHUNK : NNZ_TOTAL;
    for (int e = lo + threadIdx.x; e < hi; e += 256) {
        const int r = row[e];
        const int b = r >> 8;
        const unsigned meta = ((unsigned)(r & (BROWS - 1)) << 18) | (unsigned)col[e];
        const int p = atomicAdd(&cur[b], 1);
        tmp[p] = make_uint2(meta, __float_as_uint(val[e]));
    }
}

// per-bucket counting sort: bucket region ~137 KB -> L2-resident scatter
__global__ __launch_bounds__(256) void k_bsort(const uint2* __restrict__ tmp,
                                               uint2* __restrict__ csr,
                                               const int* __restrict__ bbase,
                                               int* __restrict__ row_offs) {
    __shared__ int cnt[BROWS];
    __shared__ int roff[BROWS];
    __shared__ int curl[BROWS];
    const int tid = threadIdx.x;
    const int b = blockIdx.x;
    const int s = bbase[b];
    const int e = bbase[b + 1];

    cnt[tid] = 0;
    __syncthreads();
    for (int j = s + tid; j < e; j += 256)
        atomicAdd(&cnt[tmp[j].x >> 18], 1);
    __syncthreads();
    if (tid == 0) {
        int a = 0;
        #pragma unroll
        for (int k = 0; k < BROWS; ++k) { roff[k] = a; a += cnt[k]; }
    }
    __syncthreads();
    {
        const int gr = b * BROWS + tid;
        if (gr < N_NODES) row_offs[gr] = s + roff[tid];
        curl[tid] = s + roff[tid];
    }
    __syncthreads();
    for (int j = s + tid; j < e; j += 256) {
        const uint2 u = tmp[j];
        const int p = atomicAdd(&curl[u.x >> 18], 1);
        csr[p] = u;
    }
    if (b == 0 && tid == 0) row_offs[N_NODES] = NNZ_TOTAL;
}

// ===========================================================================
// CSR SpMM, bf16 gather table: one wave per row; lane = sub*16 + d4.
// Accumulate f32; write next-layer bf16 table + f32 acc. Unroll-4 for MLP.
// ===========================================================================
template <bool FINAL>
__global__ __launch_bounds__(256) void k_spmm_bf16(const ushort4* __restrict__ T4,
                                                   ushort4* __restrict__ U4,
                                                   float4* __restrict__ ACC4,
                                                   const int* __restrict__ offs,
                                                   const uint2* __restrict__ csr) {
    const int lane = threadIdx.x & 63;
    const int sub  = lane >> 4;
    const int d4   = lane & 15;
    const int r = blockIdx.x * 4 + (threadIdx.x >> 6);
    const int s = offs[r];
    const int e = offs[r + 1];
    float4 acc = make_float4(0.f, 0.f, 0.f, 0.f);
    int j = s + sub;
    for (; j + 12 < e; j += 16) {
        const uint2 e0 = csr[j];
        const uint2 e1 = csr[j + 4];
        const uint2 e2 = csr[j + 8];
        const uint2 e3 = csr[j + 12];
        const ushort4 g0 = T4[(size_t)(e0.x & COLMASK) * 16 + d4];
        const ushort4 g1 = T4[(size_t)(e1.x & COLMASK) * 16 + d4];
        const ushort4 g2 = T4[(size_t)(e2.x & COLMASK) * 16 + d4];
        const ushort4 g3 = T4[(size_t)(e3.x & COLMASK) * 16 + d4];
        const float v0 = __uint_as_float(e0.y);
        const float v1 = __uint_as_float(e1.y);
        const float v2 = __uint_as_float(e2.y);
        const float v3 = __uint_as_float(e3.y);
        acc.x += v0 * bf2f(g0.x) + v1 * bf2f(g1.x) + v2 * bf2f(g2.x) + v3 * bf2f(g3.x);
        acc.y += v0 * bf2f(g0.y) + v1 * bf2f(g1.y) + v2 * bf2f(g2.y) + v3 * bf2f(g3.y);
        acc.z += v0 * bf2f(g0.z) + v1 * bf2f(g1.z) + v2 * bf2f(g2.z) + v3 * bf2f(g3.z);
        acc.w += v0 * bf2f(g0.w) + v1 * bf2f(g1.w) + v2 * bf2f(g2.w) + v3 * bf2f(g3.w);
    }
    for (; j + 4 < e; j += 8) {
        const uint2 e0 = csr[j];
        const uint2 e1 = csr[j + 4];
        const ushort4 g0 = T4[(size_t)(e0.x & COLMASK) * 16 + d4];
        const ushort4 g1 = T4[(size_t)(e1.x & COLMASK) * 16 + d4];
        const float v0 = __uint_as_float(e0.y);
        const float v1 = __uint_as_float(e1.y);
        acc.x += v0 * bf2f(g0.x) + v1 * bf2f(g1.x);
        acc.y += v0 * bf2f(g0.y) + v1 * bf2f(g1.y);
        acc.z += v0 * bf2f(g0.z) + v1 * bf2f(g1.z);
        acc.w += v0 * bf2f(g0.w) + v1 * bf2f(g1.w);
    }
    if (j < e) {
        const uint2 e0 = csr[j];
        const ushort4 g0 = T4[(size_t)(e0.x & COLMASK) * 16 + d4];
        const float v0 = __uint_as_float(e0.y);
        acc.x += v0 * bf2f(g0.x);
        acc.y += v0 * bf2f(g0.y);
        acc.z += v0 * bf2f(g0.z);
        acc.w += v0 * bf2f(g0.w);
    }
    #pragma unroll
    for (int m = 16; m <= 32; m <<= 1) {
        acc.x += __shfl_xor(acc.x, m, 64);
        acc.y += __shfl_xor(acc.y, m, 64);
        acc.z += __shfl_xor(acc.z, m, 64);
        acc.w += __shfl_xor(acc.w, m, 64);
    }
    if (sub == 0) {
        const size_t idx = (size_t)r * 16 + d4;
        float4 a = ACC4[idx];
        if (FINAL) {
            a.x = (a.x + acc.x) * 0.25f;
            a.y = (a.y + acc.y) * 0.25f;
            a.z = (a.z + acc.z) * 0.25f;
            a.w = (a.w + acc.w) * 0.25f;
            ACC4[idx] = a;
        } else {
            ushort4 t;
            t.x = f2bf(acc.x); t.y = f2bf(acc.y); t.z = f2bf(acc.z); t.w = f2bf(acc.w);
            U4[idx] = t;
            a.x += acc.x;
            a.y += acc.y;
            a.z += acc.z;
            a.w += acc.w;
            ACC4[idx] = a;
        }
    }
}

// ===========================================================================
// Last-resort fallback (round-1 atomic path; needs only 76.8 MB ws)
// ===========================================================================
__global__ __launch_bounds__(256) void k_init_f32(const float4* __restrict__ user,
                                                  const float4* __restrict__ item,
                                                  float4* __restrict__ A,
                                                  float4* __restrict__ acc) {
    const int stride = gridDim.x * blockDim.x;
    for (int i = blockIdx.x * blockDim.x + threadIdx.x; i < TOTAL4; i += stride) {
        float4 v = (i < USZ4) ? user[i] : item[i - USZ4];
        A[i] = v;
        acc[i] = v;
    }
}

__global__ __launch_bounds__(256) void k_spmm_atomic(const float* __restrict__ A,
                                                     float* __restrict__ B,
                                                     const float* __restrict__ val,
                                                     const int* __restrict__ row,
                                                     const int* __restrict__ col) {
    const int lane = threadIdx.x & 63;
    int wave = blockIdx.x * (blockDim.x >> 6) + (threadIdx.x >> 6);
    const int nw = gridDim.x * (blockDim.x >> 6);
    for (int e = wave; e < NNZ_TOTAL; e += nw) {
        const float x = A[col[e] * DIM + lane];
        unsafeAtomicAdd(&B[row[e] * DIM + lane], val[e] * x);
    }
}

__global__ __launch_bounds__(256) void k_accadd(float4* __restrict__ acc,
                                                const float4* __restrict__ B) {
    const int stride = gridDim.x * blockDim.x;
    for (int i = blockIdx.x * blockDim.x + threadIdx.x; i < TOTAL4; i += stride) {
        float4 a = acc[i];
        const float4 b = B[i];
        a.x += b.x; a.y += b.y; a.z += b.z; a.w += b.w;
        acc[i] = a;
    }
}

__global__ __launch_bounds__(256) void k_final(float4* __restrict__ acc,
                                               const float4* __restrict__ B) {
    const int stride = gridDim.x * blockDim.x;
    for (int i = blockIdx.x * blockDim.x + threadIdx.x; i < TOTAL4; i += stride) {
        float4 a = acc[i];
        const float4 b = B[i];
        a.x = (a.x + b.x) * 0.25f;
        a.y = (a.y + b.y) * 0.25f;
        a.z = (a.z + b.z) * 0.25f;
        a.w = (a.w + b.w) * 0.25f;
        acc[i] = a;
    }
}

extern "C" void kernel_launch(void* const* d_in, const int* in_sizes, int n_in,
                              void* d_out, int out_size, void* d_ws, size_t ws_size,
                              hipStream_t stream) {
    const float* user = (const float*)d_in[0];
    const float* item = (const float*)d_in[1];
    const float* val  = (const float*)d_in[2];
    const int*   row  = (const int*)d_in[3];
    const int*   col  = (const int*)d_in[4];

    float* acc = (float*)d_out;
    const int eltBlocks = 2048;

    // ws layout: [csr 80MB (overlay: cnt matrix during build)]
    //            [tmp 80MB (overlay: T0,T1 bf16 tables after bsort)]
    //            [misc: row_offs, bbase, rowsum]
    const size_t CSR_BYTES = (size_t)NNZ_TOTAL * 8;            // 80,000,000
    uint2* csr  = (uint2*)d_ws;
    int*   cnt  = (int*)d_ws;                                   // NBG ints, dead before bsort writes csr
    char*  reg1 = (char*)d_ws + CSR_BYTES;
    uint2* tmp  = (uint2*)reg1;
    ushort4* T0 = (ushort4*)reg1;                               // 19.2MB
    ushort4* T1 = T0 + TOTAL4;                                  // 19.2MB
    int* row_offs = (int*)(reg1 + CSR_BYTES);                   // N_NODES+1
    int* bbase    = row_offs + N_NODES + 1;                     // NB+1
    int* rowsum   = bbase + NB + 1;                             // NB

    const size_t needed =
        2 * CSR_BYTES + (size_t)(N_NODES + 1 + 2 * NB + 2) * 4;

    if (ws_size >= needed) {
        // ---- build bucketed CSR (no global atomics; parallel scan) ----
        k_lhist<<<GRD, 256, 0, stream>>>(row, cnt);
        k_rowsum<<<NB, 256, 0, stream>>>(cnt, rowsum);
        k_sscan<<<1, 1024, 0, stream>>>(rowsum, bbase);
        k_rowscan<<<NB, 1024, 0, stream>>>(cnt, bbase);
        k_lscatter<<<GRD, 256, 0, stream>>>(row, col, val, cnt, tmp);
        k_bsort<<<NB, 256, 0, stream>>>(tmp, csr, bbase, row_offs);

        // ---- embeddings (T0/T1 overlay tmp; tmp dead after bsort) ----
        k_init<<<eltBlocks, 256, 0, stream>>>((const float4*)user, (const float4*)item,
                                              T0, (float4*)acc);

        const int rowBlocks = N_NODES / 4;   // 37500
        k_spmm_bf16<false><<<rowBlocks, 256, 0, stream>>>(
            T0, T1, (float4*)acc, row_offs, csr);
        k_spmm_bf16<false><<<rowBlocks, 256, 0, stream>>>(
            T1, T0, (float4*)acc, row_offs, csr);
        k_spmm_bf16<true><<<rowBlocks, 256, 0, stream>>>(
            T0, T1, (float4*)acc, row_offs, csr);
        return;
    }

    // ---- last resort: atomic path ----
    float* A2 = (float*)d_ws;
    float* B2 = A2 + TOTAL;
    k_init_f32<<<eltBlocks, 256, 0, stream>>>((const float4*)user, (const float4*)item,
                                              (float4*)A2, (float4*)acc);
    float* Af = A2;
    float* Bf = B2;
    for (int layer = 0; layer < 3; ++layer) {
        hipMemsetAsync(Bf, 0, (size_t)TOTAL * sizeof(float), stream);
        k_spmm_atomic<<<2048, 256, 0, stream>>>(Af, Bf, val, row, col);
        if (layer < 2) {
            k_accadd<<<eltBlocks, 256, 0, stream>>>((float4*)acc, (const float4*)Bf);
            float* t = Af; Af = Bf; Bf = t;
        } else {
            k_final<<<eltBlocks, 256, 0, stream>>>((float4*)acc, (const float4*)Bf);
        }
    }
}